// Round 3
// baseline (481.309 us; speedup 1.0000x reference)
//
#include <hip/hip_runtime.h>
#include <hip/hip_bf16.h>

#define NN   50000
#define NE   600000
#define INF  602
#define HID  128
#define OUTF 41
#define NBLK 196   // ceil(NN/256)

typedef __attribute__((ext_vector_type(8))) short bf16x8;
typedef __attribute__((ext_vector_type(4))) float f32x4;

__device__ inline unsigned short f2bf(float x) {
    unsigned u = __float_as_uint(x);
    unsigned r = u + 0x7FFF + ((u >> 16) & 1);   // RNE
    return (unsigned short)(r >> 16);
}

#define GLL16(gp, lp) \
    __builtin_amdgcn_global_load_lds((const __attribute__((address_space(1))) unsigned int*)(gp), \
                                     (__attribute__((address_space(3))) unsigned int*)(lp), 16, 0, 0)

// ---------------- degree histogram ----------------
__global__ __launch_bounds__(256) void deg_hist_k(const int* __restrict__ src,
                                                  const int* __restrict__ dst,
                                                  int* __restrict__ cnt_out,
                                                  int* __restrict__ cnt_in, int E) {
    int e = blockIdx.x * 256 + threadIdx.x;
    if (e < E) {
        atomicAdd(&cnt_out[src[e]], 1);
        atomicAdd(&cnt_in[dst[e]], 1);
    }
}

// ---------------- scan pass 1: per-tile exclusive scan ----------------
__global__ __launch_bounds__(256) void scan1_k(const int* __restrict__ cnt,
                                               int* __restrict__ rowptr,
                                               int* __restrict__ blockSum) {
    __shared__ int tmp[256];
    int tid = threadIdx.x;
    int i = blockIdx.x * 256 + tid;
    int v = (i < NN) ? cnt[i] : 0;
    tmp[tid] = v;
    __syncthreads();
#pragma unroll
    for (int off = 1; off < 256; off <<= 1) {
        int t = (tid >= off) ? tmp[tid - off] : 0;
        __syncthreads();
        tmp[tid] += t;
        __syncthreads();
    }
    if (i < NN) rowptr[i] = tmp[tid] - v;      // tile-exclusive
    if (tid == 255) blockSum[blockIdx.x] = tmp[255];
}

// ---------------- scan pass 2+3 fused: each block sum-reduces blockSum prefix ----------------
__global__ __launch_bounds__(256) void scan23_k(int* __restrict__ rowptr,
                                                const int* __restrict__ blockSum,
                                                int* __restrict__ wcur,
                                                const int* __restrict__ cnt_out,
                                                const int* __restrict__ cnt_in,
                                                float* __restrict__ rs_out,
                                                float* __restrict__ rs_in) {
    const int tid = threadIdx.x;
    const int bid = blockIdx.x;
    int vAll = (tid < NBLK) ? blockSum[tid] : 0;
    int vPre = (tid < bid) ? vAll : 0;
#pragma unroll
    for (int o = 32; o; o >>= 1) {
        vAll += __shfl_down(vAll, o);
        vPre += __shfl_down(vPre, o);
    }
    __shared__ int sA[4], sP[4];
    if ((tid & 63) == 0) { sA[tid >> 6] = vAll; sP[tid >> 6] = vPre; }
    __syncthreads();
    int offAll = sA[0] + sA[1] + sA[2] + sA[3];
    int offPre = sP[0] + sP[1] + sP[2] + sP[3];
    int i = bid * 256 + tid;
    if (i < NN) {
        int r = rowptr[i] + offPre;
        rowptr[i] = r;
        wcur[i] = r;
        int co = cnt_out[i]; if (co < 1) co = 1;
        int ci = cnt_in[i];  if (ci < 1) ci = 1;
        rs_out[i] = rsqrtf((float)co);
        rs_in[i]  = rsqrtf((float)ci);
    }
    if (bid == NBLK - 1 && tid == 0) rowptr[NN] = offAll;
}

// ---------------- CSR fill ----------------
__global__ __launch_bounds__(256) void fill_csr_k(const int* __restrict__ src,
                                                  const int* __restrict__ dst,
                                                  int* __restrict__ wcur,
                                                  int* __restrict__ csrsrc, int E) {
    int e = blockIdx.x * 256 + threadIdx.x;
    if (e < E) {
        int p = atomicAdd(&wcur[dst[e]], 1);
        csrsrc[p] = src[e];
    }
}

// ---------------- weight prep (all weights, one dispatch) + cnt zeroing ----------------
__device__ inline void prep_w_body(const float* __restrict__ W, int K,
                                   unsigned short* __restrict__ out, int total4, int i) {
    if (i >= total4) return;
    int col = i & 127;
    int k4 = (i >> 7) << 2;
    short4 h;
    h.x = (short)f2bf((k4 + 0 < K) ? W[(size_t)(k4 + 0) * HID + col] : 0.f);
    h.y = (short)f2bf((k4 + 1 < K) ? W[(size_t)(k4 + 1) * HID + col] : 0.f);
    h.z = (short)f2bf((k4 + 2 < K) ? W[(size_t)(k4 + 2) * HID + col] : 0.f);
    h.w = (short)f2bf((k4 + 3 < K) ? W[(size_t)(k4 + 3) * HID + col] : 0.f);
    *(short4*)&out[(size_t)(k4 >> 3) * 1024 + col * 8 + (k4 & 7)] = h;
}

__global__ __launch_bounds__(256) void prep_all_k(const float* __restrict__ W1,
                                                  const float* __restrict__ W2,
                                                  const float* __restrict__ W3,
                                                  unsigned short* __restrict__ W1t,
                                                  unsigned short* __restrict__ W2t,
                                                  unsigned short* __restrict__ W3t,
                                                  int* __restrict__ cnt) {
    int b = blockIdx.x;
    if (b < 80) {
        int t = b * 256 + threadIdx.x;             // 0..20479
        prep_w_body(W1, INF, W1t, 20480, t);
        for (int i = t; i < 2 * NN; i += 20480) cnt[i] = 0;
    } else if (b < 96) {
        prep_w_body(W2, HID, W2t, 4096, (b - 80) * 256 + threadIdx.x);
    } else {
        prep_w_body(W3, HID, W3t, 4096, (b - 96) * 256 + threadIdx.x);
    }
}

// ============ gemm1 (chunked BK=128): H[n,128] = bf16( rs_out[row] * (A[row,:] @ W1) ) ============
__global__ __launch_bounds__(256) void gemm1_k(const float* __restrict__ A,
                                               const unsigned short* __restrict__ Wt,
                                               const float* __restrict__ rs_out,
                                               unsigned short* __restrict__ H, int n) {
    __shared__ __attribute__((aligned(16))) short As[64 * 136];   // 64 rows x 128 k, stride 136
    __shared__ __attribute__((aligned(16))) short Bs[16 * 1024];  // 16 kgroups x [col][8k]

    const int tid = threadIdx.x;
    const int wave = tid >> 6;
    const int lane = tid & 63;
    const int quad = lane >> 4;
    const int l16 = lane & 15;
    const int rowBase = blockIdx.x * 64;
    const int tileBase = rowBase + wave * 16;

    float4 apf[8];
    auto loadA = [&](int ch) {   // coalesced: 32 consecutive lanes span one row's 128 floats
        int kb = ch * 128;
#pragma unroll
        for (int c = 0; c < 8; ++c) {
            int f = c * 256 + tid;
            int row = f >> 5;
            int kc = (f & 31) << 2;
            int grow = rowBase + row;
            int gk = kb + kc;
            float4 v = {0.f, 0.f, 0.f, 0.f};
            if (grow < n) {
                if (gk + 3 < INF) {
                    v = *(const float4*)(A + (size_t)grow * INF + gk);
                } else {
                    if (gk + 0 < INF) v.x = A[(size_t)grow * INF + gk + 0];
                    if (gk + 1 < INF) v.y = A[(size_t)grow * INF + gk + 1];
                    if (gk + 2 < INF) v.z = A[(size_t)grow * INF + gk + 2];
                }
            }
            apf[c] = v;
        }
    };
    auto storeA = [&]() {
#pragma unroll
        for (int c = 0; c < 8; ++c) {
            int f = c * 256 + tid;
            int row = f >> 5;
            int kc = (f & 31) << 2;
            short4 h;
            h.x = (short)f2bf(apf[c].x); h.y = (short)f2bf(apf[c].y);
            h.z = (short)f2bf(apf[c].z); h.w = (short)f2bf(apf[c].w);
            *(short4*)&As[row * 136 + kc] = h;
        }
    };
    auto issueB = [&](int ch) {  // 32KB = 32 x 1KB wave-DMA
#pragma unroll
        for (int c = 0; c < 8; ++c)
            GLL16(Wt + (size_t)ch * 16384 + c * 2048 + tid * 8, &Bs[c * 2048 + tid * 8]);
    };

    f32x4 acc[8];
#pragma unroll
    for (int j = 0; j < 8; ++j) acc[j] = (f32x4){0.f, 0.f, 0.f, 0.f};

    loadA(0);
    for (int ch = 0; ch < 5; ++ch) {
        __syncthreads();             // WAR: everyone done reading previous chunk's As/Bs
        issueB(ch);
        storeA();
        __syncthreads();             // arrival: DMA drained + As visible
        if (ch + 1 < 5) loadA(ch + 1);   // prefetch next A under this chunk's compute
#pragma unroll
        for (int s = 0; s < 4; ++s) {
            bf16x8 af = *(const bf16x8*)&As[(wave * 16 + l16) * 136 + s * 32 + quad * 8];
            const short* bg = &Bs[(s * 4 + quad) * 1024 + l16 * 8];
#pragma unroll
            for (int nt = 0; nt < 8; ++nt) {
                bf16x8 bf = *(const bf16x8*)(bg + nt * 128);
                acc[nt] = __builtin_amdgcn_mfma_f32_16x16x32_bf16(af, bf, acc[nt], 0, 0, 0);
            }
        }
    }

    // epilogue: C/D layout col = nt*16 + l16, row = tileBase + quad*4 + r
#pragma unroll
    for (int r = 0; r < 4; ++r) {
        int row = tileBase + quad * 4 + r;
        if (row < n) {
            float ro = rs_out[row];
#pragma unroll
            for (int nt = 0; nt < 8; ++nt)
                H[(size_t)row * HID + nt * 16 + l16] = f2bf(acc[nt][r] * ro);
        }
    }
}

// ============ fused gather + gemm_hid ============
// Phase 1: each wave gathers its 16 dst nodes (4 passes x 4 groups of 16 lanes) from Hin
// via CSR, applies ri/bias/relu (+optional resid store), scales by ro, writes bf16 A-tile
// straight to LDS. Phase 2: 64x128x128 MFMA GEMM with W (DMA'd at kernel start) -> Hout.
// Kills the Xb global round-trip and overlaps gather latency with other blocks' MFMA.
__global__ __launch_bounds__(256) void fgath_gemm_k(const unsigned short* __restrict__ Hin,
                                                    const unsigned short* __restrict__ Wt,
                                                    const int* __restrict__ rowptr,
                                                    const int* __restrict__ csrsrc,
                                                    const float* __restrict__ rs_in,
                                                    const float* __restrict__ rs_out,
                                                    const float* __restrict__ bias,
                                                    float* __restrict__ resid,   // nullable: x (post-relu, pre-ro) fp32
                                                    unsigned short* __restrict__ Hout,
                                                    int n) {
    __shared__ __attribute__((aligned(16))) short As[64 * 136];
    __shared__ __attribute__((aligned(16))) short Bs[16384];

    const int tid = threadIdx.x;
    const int wave = tid >> 6;
    const int lane = tid & 63;
    const int g = lane >> 4;          // node slot in wave
    const int l = lane & 15;          // lane within group
    const int gbase = g << 4;
    const int rowBase = blockIdx.x * 64;

    // W DMA issued first; drains under the gather phase, consumed after the barrier.
#pragma unroll
    for (int c = 0; c < 8; ++c)
        GLL16(Wt + c * 2048 + tid * 8, &Bs[c * 2048 + tid * 8]);

    // ---- gather phase: wave fills As rows [wave*16, wave*16+16) ----
    for (int p = 0; p < 4; ++p) {
        int lrow = wave * 16 + p * 4 + g;
        int node = rowBase + lrow;
        bool alive = node < n;
        int beg = 0, end = 0;
        if (alive) { beg = rowptr[node]; end = rowptr[node + 1]; }

        float acc[8];
#pragma unroll
        for (int k = 0; k < 8; ++k) acc[k] = 0.f;

        for (int base = beg; base < end; base += 16) {
            int m = end - base; if (m > 16) m = 16;
            int idx = (l < m) ? csrsrc[base + l] : 0;
            int j = 0;
            for (; j + 3 < m; j += 4) {
                int s0 = __shfl(idx, gbase | j);
                int s1 = __shfl(idx, gbase | (j + 1));
                int s2 = __shfl(idx, gbase | (j + 2));
                int s3 = __shfl(idx, gbase | (j + 3));
                int4 u0 = *(const int4*)(Hin + (size_t)s0 * HID + l * 8);
                int4 u1 = *(const int4*)(Hin + (size_t)s1 * HID + l * 8);
                int4 u2 = *(const int4*)(Hin + (size_t)s2 * HID + l * 8);
                int4 u3 = *(const int4*)(Hin + (size_t)s3 * HID + l * 8);
#pragma unroll
                for (int q = 0; q < 4; ++q) {
                    int4 u = (q == 0) ? u0 : (q == 1) ? u1 : (q == 2) ? u2 : u3;
                    unsigned x = (unsigned)u.x, y = (unsigned)u.y, z = (unsigned)u.z, w = (unsigned)u.w;
                    acc[0] += __uint_as_float(x << 16); acc[1] += __uint_as_float(x & 0xFFFF0000u);
                    acc[2] += __uint_as_float(y << 16); acc[3] += __uint_as_float(y & 0xFFFF0000u);
                    acc[4] += __uint_as_float(z << 16); acc[5] += __uint_as_float(z & 0xFFFF0000u);
                    acc[6] += __uint_as_float(w << 16); acc[7] += __uint_as_float(w & 0xFFFF0000u);
                }
            }
            for (; j < m; ++j) {
                int s = __shfl(idx, gbase | j);
                int4 u = *(const int4*)(Hin + (size_t)s * HID + l * 8);
                unsigned x = (unsigned)u.x, y = (unsigned)u.y, z = (unsigned)u.z, w = (unsigned)u.w;
                acc[0] += __uint_as_float(x << 16); acc[1] += __uint_as_float(x & 0xFFFF0000u);
                acc[2] += __uint_as_float(y << 16); acc[3] += __uint_as_float(y & 0xFFFF0000u);
                acc[4] += __uint_as_float(z << 16); acc[5] += __uint_as_float(z & 0xFFFF0000u);
                acc[6] += __uint_as_float(w << 16); acc[7] += __uint_as_float(w & 0xFFFF0000u);
            }
        }

        if (alive) {
            float ri = rs_in[node];
            float4 b0 = *(const float4*)(bias + l * 8);
            float4 b1 = *(const float4*)(bias + l * 8 + 4);
            float v[8];
            v[0] = fmaxf(acc[0] * ri + b0.x, 0.f); v[1] = fmaxf(acc[1] * ri + b0.y, 0.f);
            v[2] = fmaxf(acc[2] * ri + b0.z, 0.f); v[3] = fmaxf(acc[3] * ri + b0.w, 0.f);
            v[4] = fmaxf(acc[4] * ri + b1.x, 0.f); v[5] = fmaxf(acc[5] * ri + b1.y, 0.f);
            v[6] = fmaxf(acc[6] * ri + b1.z, 0.f); v[7] = fmaxf(acc[7] * ri + b1.w, 0.f);
            if (resid) {
                size_t o = (size_t)node * HID + l * 8;
                *(float4*)(resid + o) = make_float4(v[0], v[1], v[2], v[3]);
                *(float4*)(resid + o + 4) = make_float4(v[4], v[5], v[6], v[7]);
            }
            float ro = rs_out[node];
            int4 h;
            h.x = (int)(((unsigned)f2bf(v[1] * ro) << 16) | f2bf(v[0] * ro));
            h.y = (int)(((unsigned)f2bf(v[3] * ro) << 16) | f2bf(v[2] * ro));
            h.z = (int)(((unsigned)f2bf(v[5] * ro) << 16) | f2bf(v[4] * ro));
            h.w = (int)(((unsigned)f2bf(v[7] * ro) << 16) | f2bf(v[6] * ro));
            *(int4*)&As[lrow * 136 + l * 8] = h;
        } else {
            *(int4*)&As[lrow * 136 + l * 8] = make_int4(0, 0, 0, 0);
        }
    }
    __syncthreads();   // As complete + W DMA drained

    // ---- GEMM phase (as gemm_hid) ----
    const int quad = lane >> 4;
    const int l16 = lane & 15;
    const int wm = wave >> 1;
    const int wn = wave & 1;

    f32x4 acc2[2][4];
#pragma unroll
    for (int i = 0; i < 2; ++i)
#pragma unroll
        for (int j = 0; j < 4; ++j) acc2[i][j] = (f32x4){0.f, 0.f, 0.f, 0.f};

#pragma unroll
    for (int kq = 0; kq < 4; ++kq) {
        bf16x8 af[2], bfr[4];
#pragma unroll
        for (int mt = 0; mt < 2; ++mt)
            af[mt] = *(const bf16x8*)&As[(wm * 32 + mt * 16 + l16) * 136 + kq * 32 + quad * 8];
#pragma unroll
        for (int nt = 0; nt < 4; ++nt)
            bfr[nt] = *(const bf16x8*)&Bs[(kq * 4 + quad) * 1024 + (wn * 64 + nt * 16 + l16) * 8];
#pragma unroll
        for (int mt = 0; mt < 2; ++mt)
#pragma unroll
            for (int nt = 0; nt < 4; ++nt)
                acc2[mt][nt] = __builtin_amdgcn_mfma_f32_16x16x32_bf16(af[mt], bfr[nt], acc2[mt][nt], 0, 0, 0);
    }

#pragma unroll
    for (int mt = 0; mt < 2; ++mt)
#pragma unroll
        for (int r = 0; r < 4; ++r) {
            int row = rowBase + wm * 32 + mt * 16 + quad * 4 + r;
            if (row < n) {
#pragma unroll
                for (int nt = 0; nt < 4; ++nt) {
                    int col = wn * 64 + nt * 16 + l16;
                    Hout[(size_t)row * HID + col] = f2bf(acc2[mt][nt][r]);
                }
            }
        }
}

// ============ fused gather + residual + FC ============
// Phase 1: gather layer-3 aggregation for this block's 64 nodes, add resid, relu -> Xs (LDS fp32).
// Phase 2: out[64,41] = Xs @ Wfc + bfc (fp32 VALU, Wfc staged in LDS).
__global__ __launch_bounds__(256) void ffc_k(const unsigned short* __restrict__ Hin,
                                             const int* __restrict__ rowptr,
                                             const int* __restrict__ csrsrc,
                                             const float* __restrict__ rs_in,
                                             const float* __restrict__ bias,   // b3
                                             const float* __restrict__ resid,
                                             const float* __restrict__ Wfc,
                                             const float* __restrict__ bfc,
                                             float* __restrict__ out, int n) {
    __shared__ float Xs[64][HID];        // 32 KB
    __shared__ float Ws[HID * OUTF];     // 21 KB

    const int tid = threadIdx.x;
    const int wave = tid >> 6;
    const int lane = tid & 63;
    const int g = lane >> 4;
    const int l = lane & 15;
    const int gbase = g << 4;
    const int rowBase = blockIdx.x * 64;

    for (int i = tid; i < HID * OUTF; i += 256) Ws[i] = Wfc[i];

    for (int p = 0; p < 4; ++p) {
        int lrow = wave * 16 + p * 4 + g;
        int node = rowBase + lrow;
        bool alive = node < n;
        int beg = 0, end = 0;
        if (alive) { beg = rowptr[node]; end = rowptr[node + 1]; }

        float acc[8];
#pragma unroll
        for (int k = 0; k < 8; ++k) acc[k] = 0.f;

        for (int base = beg; base < end; base += 16) {
            int m = end - base; if (m > 16) m = 16;
            int idx = (l < m) ? csrsrc[base + l] : 0;
            int j = 0;
            for (; j + 3 < m; j += 4) {
                int s0 = __shfl(idx, gbase | j);
                int s1 = __shfl(idx, gbase | (j + 1));
                int s2 = __shfl(idx, gbase | (j + 2));
                int s3 = __shfl(idx, gbase | (j + 3));
                int4 u0 = *(const int4*)(Hin + (size_t)s0 * HID + l * 8);
                int4 u1 = *(const int4*)(Hin + (size_t)s1 * HID + l * 8);
                int4 u2 = *(const int4*)(Hin + (size_t)s2 * HID + l * 8);
                int4 u3 = *(const int4*)(Hin + (size_t)s3 * HID + l * 8);
#pragma unroll
                for (int q = 0; q < 4; ++q) {
                    int4 u = (q == 0) ? u0 : (q == 1) ? u1 : (q == 2) ? u2 : u3;
                    unsigned x = (unsigned)u.x, y = (unsigned)u.y, z = (unsigned)u.z, w = (unsigned)u.w;
                    acc[0] += __uint_as_float(x << 16); acc[1] += __uint_as_float(x & 0xFFFF0000u);
                    acc[2] += __uint_as_float(y << 16); acc[3] += __uint_as_float(y & 0xFFFF0000u);
                    acc[4] += __uint_as_float(z << 16); acc[5] += __uint_as_float(z & 0xFFFF0000u);
                    acc[6] += __uint_as_float(w << 16); acc[7] += __uint_as_float(w & 0xFFFF0000u);
                }
            }
            for (; j < m; ++j) {
                int s = __shfl(idx, gbase | j);
                int4 u = *(const int4*)(Hin + (size_t)s * HID + l * 8);
                unsigned x = (unsigned)u.x, y = (unsigned)u.y, z = (unsigned)u.z, w = (unsigned)u.w;
                acc[0] += __uint_as_float(x << 16); acc[1] += __uint_as_float(x & 0xFFFF0000u);
                acc[2] += __uint_as_float(y << 16); acc[3] += __uint_as_float(y & 0xFFFF0000u);
                acc[4] += __uint_as_float(z << 16); acc[5] += __uint_as_float(z & 0xFFFF0000u);
                acc[6] += __uint_as_float(w << 16); acc[7] += __uint_as_float(w & 0xFFFF0000u);
            }
        }

        if (alive) {
            float ri = rs_in[node];
            float4 b0 = *(const float4*)(bias + l * 8);
            float4 b1 = *(const float4*)(bias + l * 8 + 4);
            size_t o = (size_t)node * HID + l * 8;
            float4 r0 = *(const float4*)(resid + o);
            float4 r1 = *(const float4*)(resid + o + 4);
            float v[8];
            v[0] = fmaxf(fmaxf(acc[0] * ri + b0.x, 0.f) + r0.x, 0.f);
            v[1] = fmaxf(fmaxf(acc[1] * ri + b0.y, 0.f) + r0.y, 0.f);
            v[2] = fmaxf(fmaxf(acc[2] * ri + b0.z, 0.f) + r0.z, 0.f);
            v[3] = fmaxf(fmaxf(acc[3] * ri + b0.w, 0.f) + r0.w, 0.f);
            v[4] = fmaxf(fmaxf(acc[4] * ri + b1.x, 0.f) + r1.x, 0.f);
            v[5] = fmaxf(fmaxf(acc[5] * ri + b1.y, 0.f) + r1.y, 0.f);
            v[6] = fmaxf(fmaxf(acc[6] * ri + b1.z, 0.f) + r1.z, 0.f);
            v[7] = fmaxf(fmaxf(acc[7] * ri + b1.w, 0.f) + r1.w, 0.f);
            *(float4*)&Xs[lrow][l * 8]     = make_float4(v[0], v[1], v[2], v[3]);
            *(float4*)&Xs[lrow][l * 8 + 4] = make_float4(v[4], v[5], v[6], v[7]);
        } else {
            *(float4*)&Xs[lrow][l * 8]     = make_float4(0.f, 0.f, 0.f, 0.f);
            *(float4*)&Xs[lrow][l * 8 + 4] = make_float4(0.f, 0.f, 0.f, 0.f);
        }
    }
    __syncthreads();

    // ---- FC phase: wave handles rows [wave*16, wave*16+16) ----
    float bb = (lane < OUTF) ? bfc[lane] : 0.f;
    for (int r = 0; r < 16; ++r) {
        int lrow = wave * 16 + r;
        int row = rowBase + lrow;
        if (row < n && lane < OUTF) {
            float a = bb;
#pragma unroll 4
            for (int k = 0; k < HID; k += 4) {
                float4 xv = *(const float4*)&Xs[lrow][k];   // broadcast b128 read
                a += xv.x * Ws[(k + 0) * OUTF + lane];
                a += xv.y * Ws[(k + 1) * OUTF + lane];
                a += xv.z * Ws[(k + 2) * OUTF + lane];
                a += xv.w * Ws[(k + 3) * OUTF + lane];
            }
            out[(size_t)row * OUTF + lane] = a;
        }
    }
}

extern "C" void kernel_launch(void* const* d_in, const int* in_sizes, int n_in,
                              void* d_out, int out_size, void* d_ws, size_t ws_size,
                              hipStream_t stream) {
    const float* feat = (const float*)d_in[0];
    const int* src = (const int*)d_in[1];
    const int* dst = (const int*)d_in[2];
    const float* W1 = (const float*)d_in[3];
    const float* b1 = (const float*)d_in[4];
    const float* W2 = (const float*)d_in[5];
    const float* b2 = (const float*)d_in[6];
    const float* W3 = (const float*)d_in[7];
    const float* b3 = (const float*)d_in[8];
    const float* Wfc = (const float*)d_in[9];
    const float* bfc = (const float*)d_in[10];
    float* out = (float*)d_out;

    char* w = (char*)d_ws;
    auto alloc = [&](size_t b) -> void* {
        void* p = (void*)w;
        w += (b + 255) & ~(size_t)255;
        return p;
    };
    int* cnt = (int*)alloc(2 * NN * sizeof(int));   // [cnt_out | cnt_in], zeroed in prep_all
    int* cnt_out = cnt;
    int* cnt_in  = cnt + NN;
    int* rowptr  = (int*)alloc((NN + 1) * sizeof(int));
    int* wcur    = (int*)alloc(NN * sizeof(int));
    int* csrsrc  = (int*)alloc(NE * sizeof(int));
    int* blockSum = (int*)alloc(NBLK * sizeof(int));
    float* rs_out = (float*)alloc(NN * sizeof(float));
    float* rs_in  = (float*)alloc(NN * sizeof(float));
    unsigned short* W1t = (unsigned short*)alloc(10 * 8192 * sizeof(unsigned short));
    unsigned short* W2t = (unsigned short*)alloc(16384 * sizeof(unsigned short));
    unsigned short* W3t = (unsigned short*)alloc(16384 * sizeof(unsigned short));
    unsigned short* Ha = (unsigned short*)alloc((size_t)NN * HID * sizeof(unsigned short));
    unsigned short* Hc = (unsigned short*)alloc((size_t)NN * HID * sizeof(unsigned short));
    float* resid = (float*)alloc((size_t)NN * HID * sizeof(float));

    prep_all_k<<<112, 256, 0, stream>>>(W1, W2, W3, W1t, W2t, W3t, cnt);
    deg_hist_k<<<(NE + 255) / 256, 256, 0, stream>>>(src, dst, cnt_out, cnt_in, NE);
    scan1_k<<<NBLK, 256, 0, stream>>>(cnt_in, rowptr, blockSum);
    scan23_k<<<NBLK, 256, 0, stream>>>(rowptr, blockSum, wcur, cnt_out, cnt_in, rs_out, rs_in);
    fill_csr_k<<<(NE + 255) / 256, 256, 0, stream>>>(src, dst, wcur, csrsrc, NE);

    const int gblk = (NN + 63) / 64;    // 782
    // L1 GEMM: Ha = bf16(rs_out ∘ (feat @ W1))
    gemm1_k<<<gblk, 256, 0, stream>>>(feat, W1t, rs_out, Ha, NN);
    // g1 + L2 GEMM: Hc = bf16( (relu(agg(Ha)*ri+b1)*ro) @ W2 )
    fgath_gemm_k<<<gblk, 256, 0, stream>>>(Ha, W2t, rowptr, csrsrc, rs_in, rs_out, b1,
                                           nullptr, Hc, NN);
    // g2 + L3 GEMM: resid = x2 fp32 ; Ha = bf16( (x2*ro) @ W3 )
    fgath_gemm_k<<<gblk, 256, 0, stream>>>(Hc, W3t, rowptr, csrsrc, rs_in, rs_out, b2,
                                           resid, Ha, NN);
    // g3 + residual + FC
    ffc_k<<<gblk, 256, 0, stream>>>(Ha, rowptr, csrsrc, rs_in, b3, resid, Wfc, bfc, out, NN);
}